// Round 2
// baseline (27247.931 us; speedup 1.0000x reference)
//
#include <hip/hip_runtime.h>
#include <hip/hip_bf16.h>
#include <math.h>

#define LNUM 6
#define DIM  768
#define HID  3072
#define QKVD 2304
#define NH   12
#define HD   64
#define BB   8
#define SS   1024
#define MTOT (BB*SS)

typedef _Float16 f16x8 __attribute__((ext_vector_type(8)));
typedef _Float16 f16x4 __attribute__((ext_vector_type(4)));
typedef float    f32x4 __attribute__((ext_vector_type(4)));

// ---------------- async global->LDS (16B per lane) ----------------
__device__ __forceinline__ void gload_lds16(const void* g, void* l) {
    __builtin_amdgcn_global_load_lds(
        (const __attribute__((address_space(1))) void*)g,
        (__attribute__((address_space(3))) void*)l, 16, 0, 0);
}

// ---------------- positions + pad output ----------------
__global__ __launch_bounds__(1024) void pos_kernel(const int* __restrict__ tokens,
                                                   int* __restrict__ positions,
                                                   float* __restrict__ pad_out) {
    const int b = blockIdx.x;
    const int s = threadIdx.x;
    const int tok = tokens[b*SS + s];
    const int np = (tok != 0) ? 1 : 0;
    __shared__ int sc[SS];
    sc[s] = np;
    __syncthreads();
    for (int off = 1; off < SS; off <<= 1) {
        int v = sc[s];
        if (s >= off) v += sc[s - off];
        __syncthreads();
        sc[s] = v;
        __syncthreads();
    }
    positions[b*SS + s] = np ? sc[s] : 0;
    pad_out[b*SS + s]   = np ? 0.0f : 1.0f;
}

// ---------------- embedding (dual f32 + f16 output) ----------------
__global__ __launch_bounds__(256) void embed_kernel(const int* __restrict__ tokens,
                                                    const int* __restrict__ positions,
                                                    const float* __restrict__ tok_emb,
                                                    const float* __restrict__ pos_emb,
                                                    float* __restrict__ x32,
                                                    _Float16* __restrict__ x16) {
    const int gid = blockIdx.x * 256 + threadIdx.x;   // MTOT * (DIM/4)
    const int m = gid / (DIM/4);
    const int c = (gid % (DIM/4)) * 4;
    const int tok = tokens[m];
    const int p   = positions[m];
    const float4 te = *(const float4*)(tok_emb + (size_t)tok*DIM + c);
    const float4 pe = *(const float4*)(pos_emb + (size_t)p  *DIM + c);
    float4 r;
    r.x = te.x + pe.x; r.y = te.y + pe.y; r.z = te.z + pe.z; r.w = te.w + pe.w;
    *(float4*)(x32 + (size_t)m*DIM + c) = r;
    f16x4 h; h[0] = (_Float16)r.x; h[1] = (_Float16)r.y; h[2] = (_Float16)r.z; h[3] = (_Float16)r.w;
    *(f16x4*)(x16 + (size_t)m*DIM + c) = h;
}

// ---------------- f32 -> f16 convert (weights) ----------------
__global__ __launch_bounds__(256) void cvt16_kernel(const float* __restrict__ in,
                                                    _Float16* __restrict__ out, int n4) {
    const int i = blockIdx.x * 256 + threadIdx.x;
    if (i < n4) {
        const float4 v = ((const float4*)in)[i];
        f16x4 h; h[0] = (_Float16)v.x; h[1] = (_Float16)v.y; h[2] = (_Float16)v.z; h[3] = (_Float16)v.w;
        ((f16x4*)out)[i] = h;
    }
}

// ---------------- fp16 MFMA GEMM: C = A[M,K] x W[N,K]^T + bias (+res / gelu) ----------------
// 128x128 tile, BK=64, 4 waves (2x2), 16x16x32 MFMA, global_load_lds + XOR-swizzled source.
// EPI: 0 = bias -> f32 out; 1 = bias + residual -> f32 out; 2 = bias + gelu -> f16 out
template<int EPI>
__global__ __launch_bounds__(256) void hgemm_kernel(const _Float16* __restrict__ A,
                                                    const _Float16* __restrict__ W,
                                                    const float* __restrict__ bias,
                                                    const float* __restrict__ res,
                                                    void* __restrict__ Cout,
                                                    int M, int N, int K) {
    __shared__ char lds[32768];           // As [0,16K), Bs [16K,32K)
    const int tid  = threadIdx.x;
    const int w    = tid >> 6;
    const int lane = tid & 63;
    const int wr = w >> 1, wc = w & 1;
    const int bm = blockIdx.y, bn = blockIdx.x;
    const _Float16* Arow = A + (size_t)(bm*128)*K;
    const _Float16* Brow = W + (size_t)(bn*128)*K;

    f32x4 acc[4][4] = {};

    for (int k0 = 0; k0 < K; k0 += 64) {
        // ---- stage A,B tiles: 1024 16B-units each, linear LDS dest, swizzled source ----
        #pragma unroll
        for (int i = 0; i < 4; i++) {
            const int p  = (i*4 + w)*64 + lane;     // physical unit index 0..1023
            const int r  = p >> 3;                  // tile row 0..127
            const int ul = (p & 7) ^ (r & 7);       // logical 16B-unit within row (involution)
            gload_lds16(Arow + (size_t)r*K + k0 + ul*8, lds + (i*4 + w)*1024);
            gload_lds16(Brow + (size_t)r*K + k0 + ul*8, lds + 16384 + (i*4 + w)*1024);
        }
        __syncthreads();                            // drains vmcnt before barrier
        // ---- compute: 2 k-sub steps of 32 ----
        #pragma unroll
        for (int ks = 0; ks < 2; ks++) {
            f16x8 af[4], bf[4];
            #pragma unroll
            for (int mi = 0; mi < 4; mi++) {
                const int ra = wr*64 + mi*16 + (lane & 15);
                const int ua = (ks*4 + (lane >> 4)) ^ (ra & 7);
                af[mi] = *(const f16x8*)(lds + ra*128 + ua*16);
                const int rb = wc*64 + mi*16 + (lane & 15);
                const int ub = (ks*4 + (lane >> 4)) ^ (rb & 7);
                bf[mi] = *(const f16x8*)(lds + 16384 + rb*128 + ub*16);
            }
            #pragma unroll
            for (int mi = 0; mi < 4; mi++)
                #pragma unroll
                for (int ni = 0; ni < 4; ni++)
                    acc[mi][ni] = __builtin_amdgcn_mfma_f32_16x16x32_f16(af[mi], bf[ni], acc[mi][ni], 0, 0, 0);
        }
        __syncthreads();
    }

    // ---- epilogue: C/D layout col=lane&15, row=(lane>>4)*4+reg ----
    const int lr = lane >> 4, lc = lane & 15;
    #pragma unroll
    for (int mi = 0; mi < 4; mi++) {
        #pragma unroll
        for (int r = 0; r < 4; r++) {
            const int row = bm*128 + wr*64 + mi*16 + lr*4 + r;
            #pragma unroll
            for (int ni = 0; ni < 4; ni++) {
                const int col = bn*128 + wc*64 + ni*16 + lc;
                float v = acc[mi][ni][r] + bias[col];
                if (EPI == 1) v += res[(size_t)row*N + col];
                if (EPI == 2) {
                    const float u = v;
                    v = 0.5f*u*(1.0f + tanhf(0.7978845608028654f*(u + 0.044715f*u*u*u)));
                    ((_Float16*)Cout)[(size_t)row*N + col] = (_Float16)v;
                } else {
                    ((float*)Cout)[(size_t)row*N + col] = v;
                }
            }
        }
    }
}

// ---------------- attention: 4 q-rows/block, K/V tiles staged in LDS ----------------
__global__ __launch_bounds__(256) void attn_kernel(const float* __restrict__ qkv,
                                                   const int* __restrict__ tokens,
                                                   _Float16* __restrict__ aout) {
    __shared__ float Ks[32][64];
    __shared__ float Vs[32][64];
    __shared__ int tf[32];
    const int bh = blockIdx.x >> 8;          // 0..95
    const int qg = blockIdx.x & 255;
    const int h = bh % NH, b = bh / NH;
    const int w = threadIdx.x >> 6, lane = threadIdx.x & 63;
    const int q = qg*4 + w;
    const size_t rowq = (size_t)(b*SS + q);
    const float qd = qkv[rowq*QKVD + h*HD + lane] * 0.125f;   // 1/sqrt(64)
    const float* kv0 = qkv + (size_t)b*SS*QKVD + DIM + h*HD;  // K base for this (b,h)
    float m = -3.0e38f, l = 0.0f, acc = 0.0f;
    const int qhi = qg*4 + 3;
    for (int kt = 0; kt <= qhi; kt += 32) {
        __syncthreads();
        for (int p = threadIdx.x; p < 512; p += 256) {
            const int kk = p >> 4, c = (p & 15) * 4;
            const float* src = kv0 + (size_t)(kt + kk)*QKVD + c;
            *(float4*)&Ks[kk][c] = *(const float4*)src;
            *(float4*)&Vs[kk][c] = *(const float4*)(src + DIM);
        }
        if (threadIdx.x < 32) tf[threadIdx.x] = tokens[b*SS + kt + threadIdx.x];
        __syncthreads();
        const int kmax = (q - kt < 31) ? (q - kt) : 31;
        for (int kk = 0; kk <= kmax; kk++) {
            if (tf[kk] == 0) continue;       // pad mask (wave-uniform branch)
            float s = qd * Ks[kk][lane];
            #pragma unroll
            for (int off = 32; off; off >>= 1) s += __shfl_xor(s, off);
            const float mn = fmaxf(m, s);
            const float sc = __expf(m - mn);
            const float p  = __expf(s - mn);
            l   = l*sc + p;
            acc = acc*sc + p*Vs[kk][lane];
            m = mn;
        }
    }
    const float o = (l > 0.0f) ? acc / l : 0.0f;
    aout[rowq*DIM + h*HD + lane] = (_Float16)o;
}

// ---------------- LayerNorm (row = 768), dual f32 + f16 output ----------------
__global__ __launch_bounds__(256) void ln_kernel(const float* __restrict__ in,
                                                 const float* __restrict__ g,
                                                 const float* __restrict__ b,
                                                 float* __restrict__ out32,
                                                 _Float16* __restrict__ out16) {
    const int row = blockIdx.x;
    const int t = threadIdx.x;
    const float* xr = in + (size_t)row*DIM;
    const float v0 = xr[t], v1 = xr[t+256], v2 = xr[t+512];
    __shared__ float red[4];
    __shared__ float stat[2];
    const int lane = t & 63, wid = t >> 6;
    float s = v0 + v1 + v2;
    #pragma unroll
    for (int off = 32; off; off >>= 1) s += __shfl_down(s, off);
    if (lane == 0) red[wid] = s;
    __syncthreads();
    if (t == 0) stat[0] = (red[0]+red[1]+red[2]+red[3]) * (1.0f/DIM);
    __syncthreads();
    const float mean = stat[0];
    const float d0 = v0-mean, d1 = v1-mean, d2 = v2-mean;
    float sq = d0*d0 + d1*d1 + d2*d2;
    #pragma unroll
    for (int off = 32; off; off >>= 1) sq += __shfl_down(sq, off);
    __syncthreads();
    if (lane == 0) red[wid] = sq;
    __syncthreads();
    if (t == 0) stat[1] = rsqrtf((red[0]+red[1]+red[2]+red[3]) * (1.0f/DIM) + 1e-5f);
    __syncthreads();
    const float rstd = stat[1];
    float* orow = out32 + (size_t)row*DIM;
    _Float16* hrow = out16 + (size_t)row*DIM;
    const float o0 = d0*rstd*g[t]     + b[t];
    const float o1 = d1*rstd*g[t+256] + b[t+256];
    const float o2 = d2*rstd*g[t+512] + b[t+512];
    orow[t]     = o0; orow[t+256] = o1; orow[t+512] = o2;
    hrow[t]     = (_Float16)o0; hrow[t+256] = (_Float16)o1; hrow[t+512] = (_Float16)o2;
}

extern "C" void kernel_launch(void* const* d_in, const int* in_sizes, int n_in,
                              void* d_out, int out_size, void* d_ws, size_t ws_size,
                              hipStream_t stream) {
    const int*   tokens  = (const int*)  d_in[0];
    const float* tok_emb = (const float*)d_in[1];
    const float* pos_emb = (const float*)d_in[2];
    const float* qkv_w   = (const float*)d_in[3];
    const float* qkv_b   = (const float*)d_in[4];
    const float* out_w   = (const float*)d_in[5];
    const float* out_b   = (const float*)d_in[6];
    const float* ln1_g   = (const float*)d_in[7];
    const float* ln1_b   = (const float*)d_in[8];
    const float* ff1_w   = (const float*)d_in[9];
    const float* ff1_b   = (const float*)d_in[10];
    const float* ff2_w   = (const float*)d_in[11];
    const float* ff2_b   = (const float*)d_in[12];
    const float* ln2_g   = (const float*)d_in[13];
    const float* ln2_b   = (const float*)d_in[14];

    char* ws = (char*)d_ws;
    size_t off = 0;
    auto carve = [&](size_t bytes) { char* p = ws + off; off += (bytes + 255) & ~(size_t)255; return p; };
    int*      positions = (int*)     carve((size_t)MTOT*4);
    float*    x32    = (float*)      carve((size_t)MTOT*DIM*4);
    _Float16* x16    = (_Float16*)   carve((size_t)MTOT*DIM*2);
    float*    ln1o32 = (float*)      carve((size_t)MTOT*DIM*4);
    _Float16* ln1o16 = (_Float16*)   carve((size_t)MTOT*DIM*2);
    float*    y32    = (float*)      carve((size_t)MTOT*DIM*4);
    float*    qkv32  = (float*)      carve((size_t)MTOT*QKVD*4);
    _Float16* a16    = (_Float16*)   carve((size_t)MTOT*DIM*2);
    _Float16* h16    = (_Float16*)   carve((size_t)MTOT*HID*2);
    _Float16* wq16   = (_Float16*)   carve((size_t)QKVD*DIM*2);
    _Float16* wo16   = (_Float16*)   carve((size_t)DIM*DIM*2);
    _Float16* w116   = (_Float16*)   carve((size_t)HID*DIM*2);
    _Float16* w216   = (_Float16*)   carve((size_t)DIM*HID*2);

    float* outx    = (float*)d_out;
    float* pad_out = outx + (size_t)MTOT*DIM;

    pos_kernel<<<BB, SS, 0, stream>>>(tokens, positions, pad_out);
    embed_kernel<<<(MTOT*(DIM/4))/256, 256, 0, stream>>>(tokens, positions, tok_emb, pos_emb, x32, x16);

    for (int l = 0; l < LNUM; l++) {
        // weight conversion for this layer
        cvt16_kernel<<<(QKVD*DIM/4)/256, 256, 0, stream>>>(qkv_w + (size_t)l*QKVD*DIM, wq16, QKVD*DIM/4);
        cvt16_kernel<<<(DIM*DIM/4)/256,  256, 0, stream>>>(out_w + (size_t)l*DIM*DIM,  wo16, DIM*DIM/4);
        cvt16_kernel<<<(HID*DIM/4)/256,  256, 0, stream>>>(ff1_w + (size_t)l*HID*DIM,  w116, HID*DIM/4);
        cvt16_kernel<<<(DIM*HID/4)/256,  256, 0, stream>>>(ff2_w + (size_t)l*DIM*HID,  w216, DIM*HID/4);

        hgemm_kernel<0><<<dim3(QKVD/128, MTOT/128), 256, 0, stream>>>(
            x16, wq16, qkv_b + (size_t)l*QKVD, nullptr, qkv32, MTOT, QKVD, DIM);
        attn_kernel<<<BB*NH*(SS/4), 256, 0, stream>>>(qkv32, tokens, a16);
        hgemm_kernel<1><<<dim3(DIM/128, MTOT/128), 256, 0, stream>>>(
            a16, wo16, out_b + (size_t)l*DIM, x32, y32, MTOT, DIM, DIM);
        ln_kernel<<<MTOT, 256, 0, stream>>>(y32, ln1_g + (size_t)l*DIM, ln1_b + (size_t)l*DIM, ln1o32, ln1o16);
        hgemm_kernel<2><<<dim3(HID/128, MTOT/128), 256, 0, stream>>>(
            ln1o16, w116, ff1_b + (size_t)l*HID, nullptr, h16, MTOT, HID, DIM);
        hgemm_kernel<1><<<dim3(DIM/128, MTOT/128), 256, 0, stream>>>(
            h16, w216, ff2_b + (size_t)l*DIM, ln1o32, y32, MTOT, DIM, HID);
        ln_kernel<<<MTOT, 256, 0, stream>>>(
            y32, ln2_g + (size_t)l*DIM, ln2_b + (size_t)l*DIM, (l == LNUM-1) ? outx : x32, x16);
    }
}

// Round 3
// 5309.073 us; speedup vs baseline: 5.1323x; 5.1323x over previous
//
#include <hip/hip_runtime.h>
#include <hip/hip_bf16.h>
#include <math.h>

#define LNUM 6
#define DIM  768
#define HID  3072
#define QKVD 2304
#define NH   12
#define HD   64
#define BB   8
#define SS   1024
#define MTOT (BB*SS)

typedef _Float16 f16x8 __attribute__((ext_vector_type(8)));
typedef _Float16 f16x4 __attribute__((ext_vector_type(4)));
typedef float    f32x4 __attribute__((ext_vector_type(4)));

// ---------------- async global->LDS (16B per lane) ----------------
__device__ __forceinline__ void gload_lds16(const void* g, void* l) {
    __builtin_amdgcn_global_load_lds(
        (const __attribute__((address_space(1))) void*)g,
        (__attribute__((address_space(3))) void*)l, 16, 0, 0);
}

// ---------------- positions + pad output ----------------
__global__ __launch_bounds__(1024) void pos_kernel(const int* __restrict__ tokens,
                                                   int* __restrict__ positions,
                                                   float* __restrict__ pad_out) {
    const int b = blockIdx.x;
    const int s = threadIdx.x;
    const int tok = tokens[b*SS + s];
    const int np = (tok != 0) ? 1 : 0;
    __shared__ int sc[SS];
    sc[s] = np;
    __syncthreads();
    for (int off = 1; off < SS; off <<= 1) {
        int v = sc[s];
        if (s >= off) v += sc[s - off];
        __syncthreads();
        sc[s] = v;
        __syncthreads();
    }
    positions[b*SS + s] = np ? sc[s] : 0;
    pad_out[b*SS + s]   = np ? 0.0f : 1.0f;
}

// ---------------- embedding (dual f32 + f16 output) ----------------
__global__ __launch_bounds__(256) void embed_kernel(const int* __restrict__ tokens,
                                                    const int* __restrict__ positions,
                                                    const float* __restrict__ tok_emb,
                                                    const float* __restrict__ pos_emb,
                                                    float* __restrict__ x32,
                                                    _Float16* __restrict__ x16) {
    const int gid = blockIdx.x * 256 + threadIdx.x;   // MTOT * (DIM/4)
    const int m = gid / (DIM/4);
    const int c = (gid % (DIM/4)) * 4;
    const int tok = tokens[m];
    const int p   = positions[m];
    const float4 te = *(const float4*)(tok_emb + (size_t)tok*DIM + c);
    const float4 pe = *(const float4*)(pos_emb + (size_t)p  *DIM + c);
    float4 r;
    r.x = te.x + pe.x; r.y = te.y + pe.y; r.z = te.z + pe.z; r.w = te.w + pe.w;
    *(float4*)(x32 + (size_t)m*DIM + c) = r;
    f16x4 h; h[0] = (_Float16)r.x; h[1] = (_Float16)r.y; h[2] = (_Float16)r.z; h[3] = (_Float16)r.w;
    *(f16x4*)(x16 + (size_t)m*DIM + c) = h;
}

// ---------------- f32 -> f16 convert (weights) ----------------
__global__ __launch_bounds__(256) void cvt16_kernel(const float* __restrict__ in,
                                                    _Float16* __restrict__ out, int n4) {
    const int i = blockIdx.x * 256 + threadIdx.x;
    if (i < n4) {
        const float4 v = ((const float4*)in)[i];
        f16x4 h; h[0] = (_Float16)v.x; h[1] = (_Float16)v.y; h[2] = (_Float16)v.z; h[3] = (_Float16)v.w;
        ((f16x4*)out)[i] = h;
    }
}

// ---------------- fp16 MFMA GEMM: C = A[M,K] x W[N,K]^T + bias (+res / gelu) ----------------
// 128x128 tile, BK=64, 4 waves (2x2), 16x16x32 MFMA, global_load_lds + XOR-swizzled source.
// EPI: 0 = bias -> f32 out; 1 = bias + residual -> f32 out; 2 = bias + gelu -> f16 out
template<int EPI>
__global__ __launch_bounds__(256) void hgemm_kernel(const _Float16* __restrict__ A,
                                                    const _Float16* __restrict__ W,
                                                    const float* __restrict__ bias,
                                                    const float* __restrict__ res,
                                                    void* __restrict__ Cout,
                                                    int M, int N, int K) {
    __shared__ char lds[32768];           // As [0,16K), Bs [16K,32K)
    const int tid  = threadIdx.x;
    const int w    = tid >> 6;
    const int lane = tid & 63;
    const int wr = w >> 1, wc = w & 1;
    const int bm = blockIdx.y, bn = blockIdx.x;
    const _Float16* Arow = A + (size_t)(bm*128)*K;
    const _Float16* Brow = W + (size_t)(bn*128)*K;

    f32x4 acc[4][4] = {};

    for (int k0 = 0; k0 < K; k0 += 64) {
        // ---- stage A,B tiles: 1024 16B-units each, linear LDS dest, swizzled source ----
        #pragma unroll
        for (int i = 0; i < 4; i++) {
            const int p  = (i*4 + w)*64 + lane;     // physical unit index 0..1023
            const int r  = p >> 3;                  // tile row 0..127
            const int ul = (p & 7) ^ (r & 7);       // logical 16B-unit within row (involution)
            gload_lds16(Arow + (size_t)r*K + k0 + ul*8, lds + (i*4 + w)*1024);
            gload_lds16(Brow + (size_t)r*K + k0 + ul*8, lds + 16384 + (i*4 + w)*1024);
        }
        __syncthreads();                            // drains vmcnt before barrier
        // ---- compute: 2 k-sub steps of 32 ----
        #pragma unroll
        for (int ks = 0; ks < 2; ks++) {
            f16x8 af[4], bf[4];
            #pragma unroll
            for (int mi = 0; mi < 4; mi++) {
                const int ra = wr*64 + mi*16 + (lane & 15);
                const int ua = (ks*4 + (lane >> 4)) ^ (ra & 7);
                af[mi] = *(const f16x8*)(lds + ra*128 + ua*16);
                const int rb = wc*64 + mi*16 + (lane & 15);
                const int ub = (ks*4 + (lane >> 4)) ^ (rb & 7);
                bf[mi] = *(const f16x8*)(lds + 16384 + rb*128 + ub*16);
            }
            #pragma unroll
            for (int mi = 0; mi < 4; mi++)
                #pragma unroll
                for (int ni = 0; ni < 4; ni++)
                    acc[mi][ni] = __builtin_amdgcn_mfma_f32_16x16x32_f16(af[mi], bf[ni], acc[mi][ni], 0, 0, 0);
        }
        __syncthreads();
    }

    // ---- epilogue: C/D layout col=lane&15, row=(lane>>4)*4+reg ----
    const int lr = lane >> 4, lc = lane & 15;
    #pragma unroll
    for (int mi = 0; mi < 4; mi++) {
        #pragma unroll
        for (int r = 0; r < 4; r++) {
            const int row = bm*128 + wr*64 + mi*16 + lr*4 + r;
            #pragma unroll
            for (int ni = 0; ni < 4; ni++) {
                const int col = bn*128 + wc*64 + ni*16 + lc;
                float v = acc[mi][ni][r] + bias[col];
                if (EPI == 1) v += res[(size_t)row*N + col];
                if (EPI == 2) {
                    const float u = v;
                    v = 0.5f*u*(1.0f + tanhf(0.7978845608028654f*(u + 0.044715f*u*u*u)));
                    ((_Float16*)Cout)[(size_t)row*N + col] = (_Float16)v;
                } else {
                    ((float*)Cout)[(size_t)row*N + col] = v;
                }
            }
        }
    }
}

// ---------------- attention: lane = q-row, K/V broadcast from LDS ----------------
// Block = 4 waves = 256 q-rows (interleaved: q = qb + lane*4 + wave) of one (b,h).
// Each lane: q-row in 64 VGPRs, acc in 64 VGPRs, private online softmax with
// deferred-max rescale (THR=8). K/V staged per 64-k tile; all compute-loop LDS
// reads are same-address broadcasts (conflict-free). Pad-k skip is wave-uniform.
__global__ __launch_bounds__(256) void attn_kernel(const float* __restrict__ qkv,
                                                   const int* __restrict__ tokens,
                                                   _Float16* __restrict__ aout) {
    __shared__ float Ks[64][64];
    __shared__ float Vs[64][64];
    __shared__ int tf[64];
    const int gx = blockIdx.x;
    const int qblk = 3 - (gx / 96);          // long blocks first (load balance)
    const int bh = gx % 96;
    const int h = bh % NH, b = bh / NH;
    const int w = threadIdx.x >> 6, lane = threadIdx.x & 63;
    const int ql = qblk*256 + lane*4 + w;    // this lane's q row (interleaved)
    const size_t rowq = (size_t)(b*SS + ql);
    const float* kv0 = qkv + (size_t)b*SS*QKVD + DIM + h*HD;   // K base for (b,h)

    f32x4 qv[16];
    const float* qp = qkv + rowq*QKVD + h*HD;
    #pragma unroll
    for (int i = 0; i < 16; i++) {
        qv[i] = *(const f32x4*)(qp + i*4);
        qv[i] *= 0.125f;                      // 1/sqrt(64)
    }
    f32x4 av[16] = {};
    float m = -1e30f, lsum = 0.0f;

    const int ntile = qblk*4 + 4;
    for (int t = 0; t < ntile; t++) {
        const int k0 = t*64;
        __syncthreads();
        for (int p4 = threadIdx.x; p4 < 1024; p4 += 256) {
            const int r = p4 >> 4, c = (p4 & 15)*4;
            const float* src = kv0 + (size_t)(k0 + r)*QKVD + c;
            *(float4*)&Ks[r][c] = *(const float4*)src;
            *(float4*)&Vs[r][c] = *(const float4*)(src + DIM);
        }
        if (threadIdx.x < 64) tf[threadIdx.x] = tokens[b*SS + k0 + threadIdx.x];
        __syncthreads();
        for (int kk = 0; kk < 64; kk++) {
            if (tf[kk] == 0) continue;        // pad mask, wave-uniform
            const int k = k0 + kk;
            f32x4 s4 = {};
            #pragma unroll
            for (int i = 0; i < 16; i++)
                s4 += qv[i] * *(const f32x4*)&Ks[kk][i*4];
            const float s = (s4[0] + s4[1]) + (s4[2] + s4[3]);
            const bool valid = (k <= ql);
            if (valid && s > m + 8.0f) {      // rare deferred rescale
                const float f = __expf(m - s);
                lsum *= f;
                #pragma unroll
                for (int i = 0; i < 16; i++) av[i] *= f;
                m = s;
            }
            const float p = valid ? __expf(s - m) : 0.0f;
            lsum += p;
            #pragma unroll
            for (int i = 0; i < 16; i++)
                av[i] += p * *(const f32x4*)&Vs[kk][i*4];
        }
    }
    const float inv = (lsum > 0.0f) ? 1.0f / lsum : 0.0f;
    _Float16* op = aout + rowq*DIM + h*HD;
    #pragma unroll
    for (int i = 0; i < 16; i++) {
        f16x4 o;
        o[0] = (_Float16)(av[i][0]*inv); o[1] = (_Float16)(av[i][1]*inv);
        o[2] = (_Float16)(av[i][2]*inv); o[3] = (_Float16)(av[i][3]*inv);
        *(f16x4*)(op + i*4) = o;
    }
}

// ---------------- LayerNorm (row = 768), dual f32 + f16 output ----------------
__global__ __launch_bounds__(256) void ln_kernel(const float* __restrict__ in,
                                                 const float* __restrict__ g,
                                                 const float* __restrict__ b,
                                                 float* __restrict__ out32,
                                                 _Float16* __restrict__ out16) {
    const int row = blockIdx.x;
    const int t = threadIdx.x;
    const float* xr = in + (size_t)row*DIM;
    const float v0 = xr[t], v1 = xr[t+256], v2 = xr[t+512];
    __shared__ float red[4];
    __shared__ float stat[2];
    const int lane = t & 63, wid = t >> 6;
    float s = v0 + v1 + v2;
    #pragma unroll
    for (int off = 32; off; off >>= 1) s += __shfl_down(s, off);
    if (lane == 0) red[wid] = s;
    __syncthreads();
    if (t == 0) stat[0] = (red[0]+red[1]+red[2]+red[3]) * (1.0f/DIM);
    __syncthreads();
    const float mean = stat[0];
    const float d0 = v0-mean, d1 = v1-mean, d2 = v2-mean;
    float sq = d0*d0 + d1*d1 + d2*d2;
    #pragma unroll
    for (int off = 32; off; off >>= 1) sq += __shfl_down(sq, off);
    __syncthreads();
    if (lane == 0) red[wid] = sq;
    __syncthreads();
    if (t == 0) stat[1] = rsqrtf((red[0]+red[1]+red[2]+red[3]) * (1.0f/DIM) + 1e-5f);
    __syncthreads();
    const float rstd = stat[1];
    float* orow = out32 + (size_t)row*DIM;
    _Float16* hrow = out16 + (size_t)row*DIM;
    const float o0 = d0*rstd*g[t]     + b[t];
    const float o1 = d1*rstd*g[t+256] + b[t+256];
    const float o2 = d2*rstd*g[t+512] + b[t+512];
    orow[t]     = o0; orow[t+256] = o1; orow[t+512] = o2;
    hrow[t]     = (_Float16)o0; hrow[t+256] = (_Float16)o1; hrow[t+512] = (_Float16)o2;
}

extern "C" void kernel_launch(void* const* d_in, const int* in_sizes, int n_in,
                              void* d_out, int out_size, void* d_ws, size_t ws_size,
                              hipStream_t stream) {
    const int*   tokens  = (const int*)  d_in[0];
    const float* tok_emb = (const float*)d_in[1];
    const float* pos_emb = (const float*)d_in[2];
    const float* qkv_w   = (const float*)d_in[3];
    const float* qkv_b   = (const float*)d_in[4];
    const float* out_w   = (const float*)d_in[5];
    const float* out_b   = (const float*)d_in[6];
    const float* ln1_g   = (const float*)d_in[7];
    const float* ln1_b   = (const float*)d_in[8];
    const float* ff1_w   = (const float*)d_in[9];
    const float* ff1_b   = (const float*)d_in[10];
    const float* ff2_w   = (const float*)d_in[11];
    const float* ff2_b   = (const float*)d_in[12];
    const float* ln2_g   = (const float*)d_in[13];
    const float* ln2_b   = (const float*)d_in[14];

    char* ws = (char*)d_ws;
    size_t off = 0;
    auto carve = [&](size_t bytes) { char* p = ws + off; off += (bytes + 255) & ~(size_t)255; return p; };
    int*      positions = (int*)     carve((size_t)MTOT*4);
    float*    x32    = (float*)      carve((size_t)MTOT*DIM*4);
    _Float16* x16    = (_Float16*)   carve((size_t)MTOT*DIM*2);
    float*    ln1o32 = (float*)      carve((size_t)MTOT*DIM*4);
    _Float16* ln1o16 = (_Float16*)   carve((size_t)MTOT*DIM*2);
    float*    y32    = (float*)      carve((size_t)MTOT*DIM*4);
    float*    qkv32  = (float*)      carve((size_t)MTOT*QKVD*4);
    _Float16* a16    = (_Float16*)   carve((size_t)MTOT*DIM*2);
    _Float16* h16    = (_Float16*)   carve((size_t)MTOT*HID*2);
    _Float16* wq16   = (_Float16*)   carve((size_t)QKVD*DIM*2);
    _Float16* wo16   = (_Float16*)   carve((size_t)DIM*DIM*2);
    _Float16* w116   = (_Float16*)   carve((size_t)HID*DIM*2);
    _Float16* w216   = (_Float16*)   carve((size_t)DIM*HID*2);

    float* outx    = (float*)d_out;
    float* pad_out = outx + (size_t)MTOT*DIM;

    pos_kernel<<<BB, SS, 0, stream>>>(tokens, positions, pad_out);
    embed_kernel<<<(MTOT*(DIM/4))/256, 256, 0, stream>>>(tokens, positions, tok_emb, pos_emb, x32, x16);

    for (int l = 0; l < LNUM; l++) {
        // weight conversion for this layer
        cvt16_kernel<<<(QKVD*DIM/4)/256, 256, 0, stream>>>(qkv_w + (size_t)l*QKVD*DIM, wq16, QKVD*DIM/4);
        cvt16_kernel<<<(DIM*DIM/4)/256,  256, 0, stream>>>(out_w + (size_t)l*DIM*DIM,  wo16, DIM*DIM/4);
        cvt16_kernel<<<(HID*DIM/4)/256,  256, 0, stream>>>(ff1_w + (size_t)l*HID*DIM,  w116, HID*DIM/4);
        cvt16_kernel<<<(DIM*HID/4)/256,  256, 0, stream>>>(ff2_w + (size_t)l*DIM*HID,  w216, DIM*HID/4);

        hgemm_kernel<0><<<dim3(QKVD/128, MTOT/128), 256, 0, stream>>>(
            x16, wq16, qkv_b + (size_t)l*QKVD, nullptr, qkv32, MTOT, QKVD, DIM);
        attn_kernel<<<BB*NH*4, 256, 0, stream>>>(qkv32, tokens, a16);
        hgemm_kernel<1><<<dim3(DIM/128, MTOT/128), 256, 0, stream>>>(
            a16, wo16, out_b + (size_t)l*DIM, x32, y32, MTOT, DIM, DIM);
        ln_kernel<<<MTOT, 256, 0, stream>>>(y32, ln1_g + (size_t)l*DIM, ln1_b + (size_t)l*DIM, ln1o32, ln1o16);
        hgemm_kernel<2><<<dim3(HID/128, MTOT/128), 256, 0, stream>>>(
            ln1o16, w116, ff1_b + (size_t)l*HID, nullptr, h16, MTOT, HID, DIM);
        hgemm_kernel<1><<<dim3(DIM/128, MTOT/128), 256, 0, stream>>>(
            h16, w216, ff2_b + (size_t)l*DIM, ln1o32, y32, MTOT, DIM, HID);
        ln_kernel<<<MTOT, 256, 0, stream>>>(
            y32, ln2_g + (size_t)l*DIM, ln2_b + (size_t)l*DIM, (l == LNUM-1) ? outx : x32, x16);
    }
}